// Round 4
// baseline (301.008 us; speedup 1.0000x reference)
//
#include <hip/hip_runtime.h>

typedef unsigned short u16;
typedef unsigned int u32;
typedef short bf16x8 __attribute__((ext_vector_type(8)));
typedef float f32x4 __attribute__((ext_vector_type(4)));

static constexpr int LS = 2048;   // seq len
static constexpr int DM = 1024;   // d_model
static constexpr int DI = 2048;   // d_inner
static constexpr int DSn = 16;    // d_state
static constexpr int DTRk = 64;   // dt_rank
static constexpr int MR = 4096;   // B*L rows
static constexpr int NCH = 32;    // scan chunks
static constexpr int CL = LS / NCH;  // 64 timesteps per chunk

#define DEV __device__ __forceinline__

DEV u16 f2bf(float f) {
  u32 u = __float_as_uint(f);
  u32 r = (u + 0x7FFF + ((u >> 16) & 1)) >> 16;
  return (u16)r;
}
DEV float bf2f(u16 h) { return __uint_as_float(((u32)h) << 16); }

DEV void gload16(const u16* g, u16* l) {
  __builtin_amdgcn_global_load_lds((const __attribute__((address_space(1))) u32*)g,
                                   (__attribute__((address_space(3))) u32*)l, 16, 0, 0);
}

// ---------------- converts ----------------
__global__ __launch_bounds__(256) void cvt_bf16_kernel(const float* __restrict__ in,
                                                       u16* __restrict__ out, int n) {
  int i = blockIdx.x * 256 + threadIdx.x;
  int stride = gridDim.x * 256;
  for (; i < n; i += stride) out[i] = f2bf(in[i]);
}

// W_xproj [96][2048] -> padded bf16 [128][2048] (rows 96..127 zero)
__global__ __launch_bounds__(256) void cvt_pad_xproj_kernel(const float* __restrict__ in,
                                                            u16* __restrict__ out) {
  int i = blockIdx.x * 256 + threadIdx.x;  // 128*2048
  int r = i >> 11, c = i & (DI - 1);
  out[i] = (r < 96) ? f2bf(in[r * DI + c]) : (u16)0;
}

// ---------------- RMSNorm -> bf16 ----------------
__global__ __launch_bounds__(256) void rmsnorm_kernel(const float* __restrict__ x,
                                                      const float* __restrict__ w,
                                                      u16* __restrict__ xn) {
  const int row = blockIdx.x;
  const int tid = threadIdx.x;
  const float4 v = reinterpret_cast<const float4*>(x + (size_t)row * DM)[tid];
  float ss = v.x * v.x + v.y * v.y + v.z * v.z + v.w * v.w;
#pragma unroll
  for (int o = 32; o; o >>= 1) ss += __shfl_xor(ss, o);
  __shared__ float red[4];
  if ((tid & 63) == 0) red[tid >> 6] = ss;
  __syncthreads();
  const float tot = red[0] + red[1] + red[2] + red[3];
  const float scale = rsqrtf(tot * (1.0f / DM) + 1e-5f);
  const float4 wv = reinterpret_cast<const float4*>(w)[tid];
  ushort4 o4;
  o4.x = f2bf(v.x * scale * wv.x);
  o4.y = f2bf(v.y * scale * wv.y);
  o4.z = f2bf(v.z * scale * wv.z);
  o4.w = f2bf(v.w * scale * wv.w);
  *reinterpret_cast<ushort4*>(&xn[(size_t)row * DM + tid * 4]) = o4;
}

// ---------------- MFMA GEMM: C[M,N] = A[M,K] * B[N,K]^T, bf16 in / f32 acc ----------------
template <int EPI>
__global__ __launch_bounds__(256) void gemm_bt(const u16* __restrict__ A,
                                               const u16* __restrict__ Bw,
                                               int M, int N, int K,
                                               float* __restrict__ outF,
                                               u16* __restrict__ outB,
                                               const float* __restrict__ aux,
                                               const float* __restrict__ resid) {
  __shared__ __align__(16) u16 As[128 * 32];
  __shared__ __align__(16) u16 Bs[128 * 32];
  const int tid = threadIdx.x;
  const int lane = tid & 63;
  const int wid = tid >> 6;
  const int wr = wid >> 1, wc = wid & 1;
  const int nwg = gridDim.x * gridDim.y;
  int wg = blockIdx.y * gridDim.x + blockIdx.x;
  wg = (wg & 7) * (nwg >> 3) + (wg >> 3);
  const int bn = (wg % gridDim.x) * 128;
  const int bm = (wg / gridDim.x) * 128;
  const int r0 = tid >> 2;
  const int c0 = (tid & 3) * 8;
  const int lrow = lane & 15, kq = lane >> 4;

  f32x4 acc[4][4] = {};

  const u16* Ab = A + (size_t)bm * K;
  const u16* Bb = Bw + (size_t)bn * K;

  for (int k0 = 0; k0 < K; k0 += 32) {
    gload16(Ab + (size_t)r0 * K + k0 + c0, &As[r0 * 32 + c0]);
    gload16(Ab + (size_t)(r0 + 64) * K + k0 + c0, &As[(r0 + 64) * 32 + c0]);
    gload16(Bb + (size_t)r0 * K + k0 + c0, &Bs[r0 * 32 + c0]);
    gload16(Bb + (size_t)(r0 + 64) * K + k0 + c0, &Bs[(r0 + 64) * 32 + c0]);
    __syncthreads();
    bf16x8 af[4], bfr[4];
#pragma unroll
    for (int m = 0; m < 4; ++m)
      af[m] = *reinterpret_cast<const bf16x8*>(&As[(wr * 64 + m * 16 + lrow) * 32 + kq * 8]);
#pragma unroll
    for (int n = 0; n < 4; ++n)
      bfr[n] = *reinterpret_cast<const bf16x8*>(&Bs[(wc * 64 + n * 16 + lrow) * 32 + kq * 8]);
#pragma unroll
    for (int m = 0; m < 4; ++m)
#pragma unroll
      for (int n = 0; n < 4; ++n)
        acc[m][n] = __builtin_amdgcn_mfma_f32_16x16x32_bf16(af[m], bfr[n], acc[m][n], 0, 0, 0);
    __syncthreads();
  }

#pragma unroll
  for (int m = 0; m < 4; ++m) {
#pragma unroll
    for (int n = 0; n < 4; ++n) {
      const int col = bn + wc * 64 + n * 16 + lrow;
#pragma unroll
      for (int r = 0; r < 4; ++r) {
        const int row = bm + wr * 64 + m * 16 + kq * 4 + r;
        const float v = acc[m][n][r];
        if (EPI == 0) {
          outB[(size_t)row * N + col] = f2bf(v);
        } else if (EPI == 2) {
          const float xv = v + aux[col];
          const float sp = fmaxf(xv, 0.f) + log1pf(__expf(-fabsf(xv)));
          outF[(size_t)row * N + col] = sp;
        } else {
          outF[(size_t)row * N + col] = v + resid[(size_t)row * N + col];
        }
      }
    }
  }
}

// ---------------- x_proj GEMM, split-K over 8 parts of 256 ----------------
__global__ __launch_bounds__(256) void gemm_xproj_splitk(const u16* __restrict__ A,
                                                         const u16* __restrict__ Bw,
                                                         float* __restrict__ p0,
                                                         float* __restrict__ p1) {
  __shared__ __align__(16) u16 As[128 * 32];
  __shared__ __align__(16) u16 Bs[128 * 32];
  const int tid = threadIdx.x;
  const int lane = tid & 63;
  const int wid = tid >> 6;
  const int wr = wid >> 1, wc = wid & 1;
  const int kp = blockIdx.x;
  const int bm = blockIdx.y * 128;
  const int koff = kp * 256;
  const int r0 = tid >> 2;
  const int c0 = (tid & 3) * 8;
  const int lrow = lane & 15, kq = lane >> 4;

  f32x4 acc[4][4] = {};
  const u16* Ab = A + (size_t)bm * DI + koff;
  const u16* Bb = Bw + koff;

  for (int k0 = 0; k0 < 256; k0 += 32) {
    gload16(Ab + (size_t)r0 * DI + k0 + c0, &As[r0 * 32 + c0]);
    gload16(Ab + (size_t)(r0 + 64) * DI + k0 + c0, &As[(r0 + 64) * 32 + c0]);
    gload16(Bb + (size_t)r0 * DI + k0 + c0, &Bs[r0 * 32 + c0]);
    gload16(Bb + (size_t)(r0 + 64) * DI + k0 + c0, &Bs[(r0 + 64) * 32 + c0]);
    __syncthreads();
    bf16x8 af[4], bfr[4];
#pragma unroll
    for (int m = 0; m < 4; ++m)
      af[m] = *reinterpret_cast<const bf16x8*>(&As[(wr * 64 + m * 16 + lrow) * 32 + kq * 8]);
#pragma unroll
    for (int n = 0; n < 4; ++n)
      bfr[n] = *reinterpret_cast<const bf16x8*>(&Bs[(wc * 64 + n * 16 + lrow) * 32 + kq * 8]);
#pragma unroll
    for (int m = 0; m < 4; ++m)
#pragma unroll
      for (int n = 0; n < 4; ++n)
        acc[m][n] = __builtin_amdgcn_mfma_f32_16x16x32_bf16(af[m], bfr[n], acc[m][n], 0, 0, 0);
    __syncthreads();
  }

  float* dst = (kp < 4 ? p0 : p1) + (size_t)(kp & 3) * MR * 128;
#pragma unroll
  for (int m = 0; m < 4; ++m)
#pragma unroll
    for (int n = 0; n < 4; ++n) {
      const int col = wc * 64 + n * 16 + lrow;
#pragma unroll
      for (int r = 0; r < 4; ++r) {
        const int row = bm + wr * 64 + m * 16 + kq * 4 + r;
        dst[(size_t)row * 128 + col] = acc[m][n][r];
      }
    }
}

// reduce 8 partial slices -> xdbl f32 (col<96) + dtr bf16 (col<64)
__global__ __launch_bounds__(256) void xproj_reduce(const float* __restrict__ p0,
                                                    const float* __restrict__ p1,
                                                    float* __restrict__ xdbl,
                                                    u16* __restrict__ dtr) {
  const int id = blockIdx.x * 256 + threadIdx.x;  // 4096*128
  const int row = id >> 7, col = id & 127;
  float s = 0.f;
#pragma unroll
  for (int kp = 0; kp < 4; ++kp) s += p0[(size_t)kp * MR * 128 + id];
#pragma unroll
  for (int kp = 0; kp < 4; ++kp) s += p1[(size_t)kp * MR * 128 + id];
  if (col < 96) xdbl[(size_t)row * 96 + col] = s;
  if (col < 64) dtr[(size_t)row * 64 + col] = f2bf(s);
}

// ---------------- depthwise causal conv1d + silu ----------------
__global__ __launch_bounds__(256) void conv_silu_kernel(const u16* __restrict__ xz,
                                                        const float* __restrict__ Wc,
                                                        const float* __restrict__ bc,
                                                        u16* __restrict__ uc) {
  const int id = blockIdx.x * 256 + threadIdx.x;  // 2*2048*2048 = 2^23
  const int d = id & (DI - 1);
  const int t = (id >> 11) & (LS - 1);
  const int b = id >> 22;
  const size_t rowb = (size_t)b * LS;
  const float4 w = *reinterpret_cast<const float4*>(&Wc[d * 4]);
  const float wv[4] = {w.x, w.y, w.z, w.w};
  float s = bc[d];
#pragma unroll
  for (int k = 0; k < 4; ++k) {
    const int tt = t - 3 + k;
    if (tt >= 0) s += bf2f(xz[(rowb + tt) * (2 * DI) + d]) * wv[k];
  }
  const float sl = s / (1.f + __expf(-s));
  uc[(rowb + t) * DI + d] = f2bf(sl);
}

// ---------------- chunked selective scan, LDS-staged ----------------
// Block = (b, chunk c, 64 consecutive d). 256 threads = 64 d x 4 ng.
// blk: db = blk&31 (d0=db*64), c = (blk>>5)&31, b = blk>>10. Grid 2048.

static constexpr float L2E = 1.44269504f;

// Phase 1: local scan from h=0; emit S (final local state) and P = exp(A*sum_dt).
__global__ __launch_bounds__(256) void scan_phase1(const float* __restrict__ dtf,
                                                   const float* __restrict__ xdbl,
                                                   const u16* __restrict__ uc,
                                                   const float* __restrict__ Alog,
                                                   float* __restrict__ P,
                                                   float* __restrict__ S) {
  __shared__ __align__(16) float s_dt[64 * 64];  // 16KB
  __shared__ __align__(16) u16 s_uc[64 * 64];    // 8KB
  __shared__ __align__(16) float s_b[64 * 16];   // 4KB
  const int tid = threadIdx.x;
  const int lane = tid & 63;
  const int w = tid >> 6;
  const int blk = blockIdx.x;
  const int d0 = (blk & 31) * 64;
  const int c = (blk >> 5) & (NCH - 1);
  const int b = blk >> 10;
  const int d_loc = tid >> 2;
  const int ng = tid & 3;
  const int d = d0 + d_loc;
  const size_t tbase = (size_t)b * LS + c * CL;

  // stage dt tile [64 t][64 d] f32 (rows 256B; 4 rows per 1KB wave-instr)
  {
    const int r = lane >> 4, col = (lane & 15) * 4;
#pragma unroll
    for (int j = 0; j < 4; ++j) {
      const int row = w * 16 + j * 4 + r;
      gload16((const u16*)(dtf + (tbase + row) * DI + d0 + col), (u16*)&s_dt[row * 64 + col]);
    }
  }
  // stage uc tile [64][64] bf16 (rows 128B; 8 rows/instr)
  {
    const int r = lane >> 3, col = (lane & 7) * 8;
#pragma unroll
    for (int j = 0; j < 2; ++j) {
      const int row = w * 16 + j * 8 + r;
      gload16(uc + (tbase + row) * DI + d0 + col, &s_uc[row * 64 + col]);
    }
  }
  // stage B tile [64][16] f32 (rows 64B; 16 rows/instr)
  {
    const int row = w * 16 + (lane >> 2), col = (lane & 3) * 4;
    gload16((const u16*)(xdbl + (tbase + row) * 96 + DTRk + col), (u16*)&s_b[row * 16 + col]);
  }

  const float4 Alv = *reinterpret_cast<const float4*>(&Alog[d * DSn + ng * 4]);
  const float Ar[4] = {-__expf(Alv.x) * L2E, -__expf(Alv.y) * L2E,
                       -__expf(Alv.z) * L2E, -__expf(Alv.w) * L2E};
  float h0 = 0.f, h1 = 0.f, h2 = 0.f, h3 = 0.f, sdt = 0.f;
  __syncthreads();

  for (int t = 0; t < CL; ++t) {
    const float dtv = s_dt[t * 64 + d_loc];
    const float uv = bf2f(s_uc[t * 64 + d_loc]);
    const float4 Bv = *reinterpret_cast<const float4*>(&s_b[t * 16 + ng * 4]);
    const float du = dtv * uv;
    sdt += dtv;
    h0 = exp2f(dtv * Ar[0]) * h0 + du * Bv.x;
    h1 = exp2f(dtv * Ar[1]) * h1 + du * Bv.y;
    h2 = exp2f(dtv * Ar[2]) * h2 + du * Bv.z;
    h3 = exp2f(dtv * Ar[3]) * h3 + du * Bv.w;
  }
  const size_t oi = (((size_t)b * NCH + c) * DI + d) * DSn + ng * 4;
  float4 Sv = {h0, h1, h2, h3};
  float4 Pv = {exp2f(Ar[0] * sdt), exp2f(Ar[1] * sdt), exp2f(Ar[2] * sdt), exp2f(Ar[3] * sdt)};
  *reinterpret_cast<float4*>(&S[oi]) = Sv;
  *reinterpret_cast<float4*>(&P[oi]) = Pv;
}

// Phase 2: serial compose over chunks; overwrite S with Hin (state entering each chunk).
// One thread per (b,d,ng): 16384 threads.
__global__ __launch_bounds__(256) void scan_phase2(const float* __restrict__ P,
                                                   float* __restrict__ S) {
  const int gid = blockIdx.x * 256 + threadIdx.x;
  const int ng = gid & 3;
  const int d = (gid >> 2) & (DI - 1);
  const int b = gid >> 13;
  float4 h = {0.f, 0.f, 0.f, 0.f};
  for (int cc = 0; cc < NCH; ++cc) {
    const size_t oi = (((size_t)b * NCH + cc) * DI + d) * DSn + ng * 4;
    const float4 Pv = *reinterpret_cast<const float4*>(&P[oi]);
    const float4 Sv = *reinterpret_cast<const float4*>(&S[oi]);
    *reinterpret_cast<float4*>(&S[oi]) = h;
    h.x = Sv.x + Pv.x * h.x;
    h.y = Sv.y + Pv.y * h.y;
    h.z = Sv.z + Pv.z * h.z;
    h.w = Sv.w + Pv.w * h.w;
  }
}

// Phase 3: h = Hin; re-scan chunk computing y, +D*u, gate silu(z), store bf16 y.
__global__ __launch_bounds__(256) void scan_phase3(const float* __restrict__ dtf,
                                                   const float* __restrict__ xdbl,
                                                   const u16* __restrict__ uc,
                                                   const u16* __restrict__ xz,
                                                   const float* __restrict__ Alog,
                                                   const float* __restrict__ Dp,
                                                   const float* __restrict__ Hin,
                                                   u16* __restrict__ yb) {
  __shared__ __align__(16) float s_dt[64 * 64];  // 16KB
  __shared__ __align__(16) u16 s_uc[64 * 64];    // 8KB
  __shared__ __align__(16) u16 s_z[64 * 64];     // 8KB (z in, y out)
  __shared__ __align__(16) float s_bc[64 * 32];  // 8KB (B|C per t)
  const int tid = threadIdx.x;
  const int lane = tid & 63;
  const int w = tid >> 6;
  const int blk = blockIdx.x;
  const int d0 = (blk & 31) * 64;
  const int c = (blk >> 5) & (NCH - 1);
  const int b = blk >> 10;
  const int d_loc = tid >> 2;
  const int ng = tid & 3;
  const int d = d0 + d_loc;
  const size_t tbase = (size_t)b * LS + c * CL;

  {
    const int r = lane >> 4, col = (lane & 15) * 4;
#pragma unroll
    for (int j = 0; j < 4; ++j) {
      const int row = w * 16 + j * 4 + r;
      gload16((const u16*)(dtf + (tbase + row) * DI + d0 + col), (u16*)&s_dt[row * 64 + col]);
    }
  }
  {
    const int r = lane >> 3, col = (lane & 7) * 8;
#pragma unroll
    for (int j = 0; j < 2; ++j) {
      const int row = w * 16 + j * 8 + r;
      gload16(uc + (tbase + row) * DI + d0 + col, &s_uc[row * 64 + col]);
      gload16(xz + (tbase + row) * (2 * DI) + DI + d0 + col, &s_z[row * 64 + col]);
    }
  }
  {
    const int r = lane >> 3, colf = (lane & 7) * 4;
#pragma unroll
    for (int j = 0; j < 2; ++j) {
      const int row = w * 16 + j * 8 + r;
      gload16((const u16*)(xdbl + (tbase + row) * 96 + DTRk + colf), (u16*)&s_bc[row * 32 + colf]);
    }
  }

  const float4 Alv = *reinterpret_cast<const float4*>(&Alog[d * DSn + ng * 4]);
  const float Ar[4] = {-__expf(Alv.x) * L2E, -__expf(Alv.y) * L2E,
                       -__expf(Alv.z) * L2E, -__expf(Alv.w) * L2E};
  const float Dd = Dp[d];
  const size_t oi = (((size_t)b * NCH + c) * DI + d) * DSn + ng * 4;
  const float4 h_in = *reinterpret_cast<const float4*>(&Hin[oi]);
  float h0 = h_in.x, h1 = h_in.y, h2 = h_in.z, h3 = h_in.w;
  __syncthreads();

  for (int t = 0; t < CL; ++t) {
    const float dtv = s_dt[t * 64 + d_loc];
    const float uv = bf2f(s_uc[t * 64 + d_loc]);
    const float4 Bv = *reinterpret_cast<const float4*>(&s_bc[t * 32 + ng * 4]);
    const float4 Cv = *reinterpret_cast<const float4*>(&s_bc[t * 32 + 16 + ng * 4]);
    const float du = dtv * uv;
    h0 = exp2f(dtv * Ar[0]) * h0 + du * Bv.x;
    h1 = exp2f(dtv * Ar[1]) * h1 + du * Bv.y;
    h2 = exp2f(dtv * Ar[2]) * h2 + du * Bv.z;
    h3 = exp2f(dtv * Ar[3]) * h3 + du * Bv.w;
    float y = h0 * Cv.x + h1 * Cv.y + h2 * Cv.z + h3 * Cv.w;
    y += __shfl_xor(y, 1);
    y += __shfl_xor(y, 2);
    if (ng == 0) {
      const float z = bf2f(s_z[t * 64 + d_loc]);
      const float sz = z / (1.f + __expf(-z));
      s_z[t * 64 + d_loc] = f2bf((y + uv * Dd) * sz);  // own slot; no cross-thread use
    }
  }
  __syncthreads();
  // burst-store y tile [64][64] bf16
  {
    const int colg = (tid & 7) * 8;
#pragma unroll
    for (int j = 0; j < 2; ++j) {
      const int row = j * 32 + (tid >> 3);
      *reinterpret_cast<bf16x8*>(&yb[(tbase + row) * DI + d0 + colg]) =
          *reinterpret_cast<const bf16x8*>(&s_z[row * 64 + colg]);
    }
  }
}

extern "C" void kernel_launch(void* const* d_in, const int* in_sizes, int n_in,
                              void* d_out, int out_size, void* d_ws, size_t ws_size,
                              hipStream_t stream) {
  (void)in_sizes; (void)n_in; (void)out_size; (void)ws_size;
  const float* x      = (const float*)d_in[0];
  const float* norm_w = (const float*)d_in[1];
  const float* W_in   = (const float*)d_in[2];
  const float* W_conv = (const float*)d_in[3];
  const float* b_conv = (const float*)d_in[4];
  const float* W_xp   = (const float*)d_in[5];
  const float* W_dt   = (const float*)d_in[6];
  const float* b_dt   = (const float*)d_in[7];
  const float* A_log  = (const float*)d_in[8];
  const float* Dvec   = (const float*)d_in[9];
  const float* W_out  = (const float*)d_in[10];
  float* out = (float*)d_out;

  char* ws = (char*)d_ws;
  size_t off = 0;
  auto alloc = [&](size_t bytes) -> void* {
    void* p = ws + off;
    off += (bytes + 255) & ~(size_t)255;
    return p;
  };
  u16* Win_b  = (u16*)alloc((size_t)4096 * 1024 * 2);   // 8 MB (dead after gemm<0>)
  u16* Wout_b = (u16*)alloc((size_t)1024 * 2048 * 2);
  u16* Wxp_b  = (u16*)alloc((size_t)128 * 2048 * 2);
  u16* Wdt_b  = (u16*)alloc((size_t)2048 * 64 * 2);
  u16* xn_b   = (u16*)alloc((size_t)MR * DM * 2);       // 8 MB (dead after gemm<0>)
  u16* xz_b   = (u16*)alloc((size_t)MR * 2 * DI * 2);
  u16* uc_b   = (u16*)alloc((size_t)MR * DI * 2);
  float* xdbl = (float*)alloc((size_t)MR * 96 * 4);
  u16* dtr_b  = (u16*)alloc((size_t)MR * 64 * 2);
  float* dtf  = (float*)alloc((size_t)MR * DI * 4);
  u16* y_b    = (u16*)alloc((size_t)MR * DI * 2);
  // Aliased scratch: split-K partials, then scan P / S(->Hin), each exactly 8 MB.
  float* part0 = (float*)Win_b;
  float* part1 = (float*)xn_b;
  float* Pbuf = (float*)Win_b;
  float* Sbuf = (float*)xn_b;

  cvt_bf16_kernel<<<2048, 256, 0, stream>>>(W_in, Win_b, 4096 * 1024);
  cvt_bf16_kernel<<<2048, 256, 0, stream>>>(W_out, Wout_b, 1024 * 2048);
  cvt_bf16_kernel<<<512, 256, 0, stream>>>(W_dt, Wdt_b, 2048 * 64);
  cvt_pad_xproj_kernel<<<1024, 256, 0, stream>>>(W_xp, Wxp_b);

  rmsnorm_kernel<<<MR, 256, 0, stream>>>(x, norm_w, xn_b);

  // xz = xn @ W_in^T : [4096,4096]
  gemm_bt<0><<<dim3(32, 32), 256, 0, stream>>>(xn_b, Win_b, MR, 4096, 1024,
                                               nullptr, xz_b, nullptr, nullptr);
  // depthwise conv + silu -> u_conv
  conv_silu_kernel<<<32768, 256, 0, stream>>>(xz_b, W_conv, b_conv, uc_b);
  // x_dbl = u_conv @ W_xproj^T : [4096,96] via split-K(8) + reduce
  gemm_xproj_splitk<<<dim3(8, 32), 256, 0, stream>>>(uc_b, Wxp_b, part0, part1);
  xproj_reduce<<<2048, 256, 0, stream>>>(part0, part1, xdbl, dtr_b);
  // dt = softplus(dtr @ W_dt^T + b_dt) : [4096,2048]
  gemm_bt<2><<<dim3(16, 32), 256, 0, stream>>>(dtr_b, Wdt_b, MR, 2048, 64,
                                               dtf, nullptr, b_dt, nullptr);
  // chunked selective scan: local scans -> compose (S:=Hin) -> rescan+gate
  scan_phase1<<<2048, 256, 0, stream>>>(dtf, xdbl, uc_b, A_log, Pbuf, Sbuf);
  scan_phase2<<<64, 256, 0, stream>>>(Pbuf, Sbuf);
  scan_phase3<<<2048, 256, 0, stream>>>(dtf, xdbl, uc_b, xz_b, A_log, Dvec,
                                        Sbuf, y_b);
  // out = y @ W_out^T + x
  gemm_bt<3><<<dim3(8, 32), 256, 0, stream>>>(y_b, Wout_b, MR, 1024, 2048,
                                              out, nullptr, nullptr, x);
}